// Round 3
// baseline (349.071 us; speedup 1.0000x reference)
//
#include <hip/hip_runtime.h>

// ---------------------------------------------------------------------------
// GraphSAGE 2-layer, mean aggregation.
//   L1: h = relu( mean_nbr(x) @ W_l1 + x @ W_r1 + b1 )   (IN=2 -> aggregate x first)
//   L2: out = mean_nbr(h) @ W_l2 + h @ W_r2 + b2
// R2: CSR via 2-level MSD binning (bucket = dst>>7).
// R4: k_agg2 gathers h in fp8 e4m3; ebuf packed to 1 uint.
// R6: k_agg2: 8 nodes/wave, 8 lanes/node, 16 cols/lane; k_agg1 folded into
//     k_bucket_csr (x-sum via LDS float atomics).
// R7: FAILED (global counting sort): 1-block scan 233us; device-scope random
//     atomics ~200us. Reverted.
// R8: NEUTRAL/REGRESSED (XCD-seg ebuf, 261.9 vs 250.7): run length per
//     (block,bucket) unchanged (~20B), only line ownership moved. Reverted.
// R9: k_bscatter pass-1 eliminated: k_bhist stores per-block histogram
//     hcnt[block][bucket] (u16, coalesced row); k_colpre (4 blocks) computes
//     rel[block][bucket] = exclusive prefix along block axis (coalesced
//     column walk); k_bscatter computes base = bbase + rel directly -> no
//     edge re-read, no global cursor atomics, no histogram LDS atomics.
//     k_agg2: edge loop unroll 2 -> 4 (double outstanding 16B gathers).
// ---------------------------------------------------------------------------

using f32x4 = __attribute__((ext_vector_type(4))) float;
using f32x2 = __attribute__((ext_vector_type(2))) float;
using s16x8 = __attribute__((ext_vector_type(8))) short;

__device__ __forceinline__ unsigned short f32_to_bf16(float f) {
  unsigned int u = __float_as_uint(f);
  u += 0x7fffu + ((u >> 16) & 1u);          // round-to-nearest-even
  return (unsigned short)(u >> 16);
}

#define EDGE_TILE 4096

// ---- bin pass 1: bucket histogram; stores per-block row + bucket totals -----
__global__ __launch_bounds__(256) void k_bhist(const int* __restrict__ ei, int* __restrict__ bcnt,
                                               unsigned short* __restrict__ hcnt, int E, int nb) {
  __shared__ int h[1024];
  int t = threadIdx.x;
  for (int i = t; i < nb; i += 256) h[i] = 0;
  __syncthreads();
  int tbeg = blockIdx.x * EDGE_TILE;
  int tend = min(tbeg + EDGE_TILE, E);
  const int* dstp = ei + E;
  for (int i = tbeg + t; i < tend; i += 256) atomicAdd(&h[dstp[i] >> 7], 1);
  __syncthreads();
  unsigned short* hr = hcnt + (size_t)blockIdx.x * nb;
  for (int i = t; i < nb; i += 256) {
    int c = h[i];
    hr[i] = (unsigned short)c;              // c <= EDGE_TILE=4096, fits u16
    if (c) atomicAdd(&bcnt[i], c);
  }
}

// ---- bin pass 2a: scan bucket totals -> bucket bases ------------------------
__global__ __launch_bounds__(1024) void k_bscan(const int* __restrict__ bcnt, int* __restrict__ bbase,
                                                int nb, int E) {
  __shared__ int sm[2][1024];
  int t = threadIdx.x;
  int v0 = (t < nb) ? bcnt[t] : 0;
  sm[0][t] = v0;
  __syncthreads();
  int src = 0;
  for (int st = 1; st < 1024; st <<= 1) {
    int v = sm[src][t];
    if (t >= st) v += sm[src][t - st];
    sm[src ^ 1][t] = v; __syncthreads(); src ^= 1;
  }
  if (t < nb) bbase[t] = sm[src][t] - v0;   // exclusive prefix
  if (t == 0) bbase[nb] = E;
}

// ---- bin pass 2b: per-(block,bucket) prefix along block axis ----------------
// One thread per bucket; iteration t reads/writes a coalesced 782-wide row.
// Per-bucket running total <= bucket size (~2300 here) -> u16 safe.
__global__ __launch_bounds__(256) void k_colpre(const unsigned short* __restrict__ hcnt,
                                                unsigned short* __restrict__ rel,
                                                int nblk, int nb) {
  int b = blockIdx.x * 256 + threadIdx.x;
  if (b >= nb) return;
  int run = 0;
  for (int t = 0; t < nblk; ++t) {
    size_t idx = (size_t)t * nb + b;
    int c = hcnt[idx];
    rel[idx] = (unsigned short)run;
    run += c;
  }
}

// ---- bin pass 3: scatter packed (src<<7 | dst&127) at precomputed bases -----
__global__ __launch_bounds__(256) void k_bscatter(const int* __restrict__ ei,
                                                  const int* __restrict__ bbase,
                                                  const unsigned short* __restrict__ rel,
                                                  unsigned int* __restrict__ ebuf, int E, int nb) {
  __shared__ int h[1024];                    // in-block rank cursors
  __shared__ int base[1024];
  int t = threadIdx.x;
  const unsigned short* rr = rel + (size_t)blockIdx.x * nb;
  for (int i = t; i < nb; i += 256) {
    h[i] = 0;
    base[i] = bbase[i] + (int)rr[i];
  }
  __syncthreads();
  int tbeg = blockIdx.x * EDGE_TILE;
  int tend = min(tbeg + EDGE_TILE, E);
  const int* srcp = ei;
  const int* dstp = ei + E;
  for (int i = tbeg + t; i < tend; i += 256) {
    int d = dstp[i];
    int b = d >> 7;
    int r = atomicAdd(&h[b], 1);
    ebuf[base[b] + r] = ((unsigned)srcp[i] << 7) | (unsigned)(d & 127);
  }
}

// ---- bin pass 4: per-bucket CSR build + layer-1 x aggregation ---------------
__global__ __launch_bounds__(256) void k_bucket_csr(const unsigned int* __restrict__ ebuf,
                                                    const int* __restrict__ bbase,
                                                    const float* __restrict__ x,
                                                    int* __restrict__ offs, int* __restrict__ csr,
                                                    float* __restrict__ agg1,
                                                    int N, int nb) {
  __shared__ int deg[128];
  __shared__ int loff[128];
  __shared__ int cur[128];
  __shared__ float sx0[128];
  __shared__ float sx1[128];
  int b = blockIdx.x;
  int t = threadIdx.x;
  int lo = bbase[b], hi = bbase[b + 1];
  if (t < 128) { deg[t] = 0; sx0[t] = 0.f; sx1[t] = 0.f; }
  __syncthreads();
  const float2* x2 = (const float2*)x;
  for (int i = lo + t; i < hi; i += 256) {
    unsigned int e = ebuf[i];
    int d = e & 127;
    float2 v = x2[e >> 7];
    atomicAdd(&deg[d], 1);
    atomicAdd(&sx0[d], v.x);
    atomicAdd(&sx1[d], v.y);
  }
  __syncthreads();
  if (t < 128) loff[t] = deg[t];
  __syncthreads();
  for (int st = 1; st < 128; st <<= 1) {
    int v = 0;
    if (t < 128 && t >= st) v = loff[t - st];
    __syncthreads();
    if (t < 128) loff[t] += v;
    __syncthreads();
  }
  if (t < 128) {
    int ex = loff[t] - deg[t];                 // exclusive prefix
    cur[t] = ex;
    int node = b * 128 + t;
    if (node < N) {
      offs[node] = lo + ex;
      agg1[2 * node]     = sx0[t];
      agg1[2 * node + 1] = sx1[t];
    }
  }
  if (b == nb - 1 && t == 0) offs[N] = hi;
  __syncthreads();
  for (int i = lo + t; i < hi; i += 256) {
    unsigned int e = ebuf[i];
    int r = atomicAdd(&cur[e & 127], 1);
    csr[lo + r] = (int)(e >> 7);
  }
}

// ---- layer-1 dense: h = relu(...), bf16 + fp8 out; 2 cols/thread ------------
__global__ __launch_bounds__(256) void k_layer1(const float* __restrict__ x, const float* __restrict__ agg1,
                                                const int* __restrict__ offs,
                                                const float* __restrict__ Wl, const float* __restrict__ Wr,
                                                const float* __restrict__ b1,
                                                unsigned int* __restrict__ h16,
                                                unsigned short* __restrict__ h8, int n) {
  int gid = blockIdx.x * 256 + threadIdx.x;
  int node = gid >> 6;
  if (node >= n) return;
  int c = (gid & 63) * 2;
  int deg = offs[node + 1] - offs[node];
  float sc = 1.0f / (float)max(deg, 1);
  float a0 = agg1[2 * node] * sc, a1 = agg1[2 * node + 1] * sc;
  float x0 = x[2 * node], x1 = x[2 * node + 1];
  float r0 = fmaf(a0, Wl[c],     fmaf(a1, Wl[128 + c],     fmaf(x0, Wr[c],     fmaf(x1, Wr[128 + c],     b1[c]))));
  float r1 = fmaf(a0, Wl[c + 1], fmaf(a1, Wl[128 + c + 1], fmaf(x0, Wr[c + 1], fmaf(x1, Wr[128 + c + 1], b1[c + 1]))));
  r0 = r0 > 0.f ? r0 : 0.f;
  r1 = r1 > 0.f ? r1 : 0.f;
  unsigned int packed = (unsigned int)f32_to_bf16(r0) | ((unsigned int)f32_to_bf16(r1) << 16);
  h16[(size_t)node * 64 + (gid & 63)] = packed;
  unsigned int p8 = (unsigned int)__builtin_amdgcn_cvt_pk_fp8_f32(r0, r1, 0, false);
  h8[(size_t)node * 64 + (gid & 63)] = (unsigned short)(p8 & 0xffffu);
}

// ---- prep: Wt[col][k] bf16, k<128 from W_l2, k>=128 from W_r2 ---------------
__global__ __launch_bounds__(256) void k_prepw(const float* __restrict__ Wl2, const float* __restrict__ Wr2,
                                               unsigned short* __restrict__ wt) {
  int tid = blockIdx.x * 256 + threadIdx.x;   // tid = c*256 + k
  if (tid >= 128 * 256) return;
  int c = tid >> 8, k = tid & 255;
  float v = (k < 128) ? Wl2[k * 128 + c] : Wr2[(k - 128) * 128 + c];
  wt[tid] = f32_to_bf16(v);
}

// ---- layer-2 aggregation: 8 nodes/wave, 8 lanes/node, 16 cols/lane ----------
#define ACC8(v)                                                                              \
  do {                                                                                       \
    f32x2 p;                                                                                 \
    p = __builtin_amdgcn_cvt_pk_f32_fp8((int)(v).x, false); acc[0] += p[0];  acc[1] += p[1]; \
    p = __builtin_amdgcn_cvt_pk_f32_fp8((int)(v).x, true);  acc[2] += p[0];  acc[3] += p[1]; \
    p = __builtin_amdgcn_cvt_pk_f32_fp8((int)(v).y, false); acc[4] += p[0];  acc[5] += p[1]; \
    p = __builtin_amdgcn_cvt_pk_f32_fp8((int)(v).y, true);  acc[6] += p[0];  acc[7] += p[1]; \
    p = __builtin_amdgcn_cvt_pk_f32_fp8((int)(v).z, false); acc[8] += p[0];  acc[9] += p[1]; \
    p = __builtin_amdgcn_cvt_pk_f32_fp8((int)(v).z, true);  acc[10] += p[0]; acc[11] += p[1];\
    p = __builtin_amdgcn_cvt_pk_f32_fp8((int)(v).w, false); acc[12] += p[0]; acc[13] += p[1];\
    p = __builtin_amdgcn_cvt_pk_f32_fp8((int)(v).w, true);  acc[14] += p[0]; acc[15] += p[1];\
  } while (0)

__global__ __launch_bounds__(256) void k_agg2(const int* __restrict__ offs, const int* __restrict__ csr,
                                              const unsigned char* __restrict__ h8,
                                              unsigned int* __restrict__ a16, int n) {
  int wv   = threadIdx.x >> 6;
  int lane = threadIdx.x & 63;
  int sub  = lane >> 3;          // node slot within wave: 0..7
  int cb   = lane & 7;           // 16-col block: cols cb*16 .. cb*16+15
  int node = blockIdx.x * 32 + wv * 8 + sub;
  if (node >= n) return;
  int beg = offs[node];
  int end = offs[node + 1];
  int deg = end - beg;
  const unsigned char* hb = h8 + cb * 16;

  float acc[16];
#pragma unroll
  for (int j = 0; j < 16; ++j) acc[j] = 0.f;

  int t = 0;
  for (; t + 3 < deg; t += 4) {              // R9: 4 gathers in flight/lane
    int s0 = csr[beg + t];
    int s1 = csr[beg + t + 1];
    int s2 = csr[beg + t + 2];
    int s3 = csr[beg + t + 3];
    uint4 v0 = *(const uint4*)(hb + (size_t)s0 * 128);
    uint4 v1 = *(const uint4*)(hb + (size_t)s1 * 128);
    uint4 v2 = *(const uint4*)(hb + (size_t)s2 * 128);
    uint4 v3 = *(const uint4*)(hb + (size_t)s3 * 128);
    ACC8(v0);
    ACC8(v1);
    ACC8(v2);
    ACC8(v3);
  }
  for (; t < deg; ++t) {
    int s0 = csr[beg + t];
    uint4 v0 = *(const uint4*)(hb + (size_t)s0 * 128);
    ACC8(v0);
  }

  float scale = 1.0f / (float)max(deg, 1);
  unsigned int u[8];
#pragma unroll
  for (int k = 0; k < 8; ++k)
    u[k] = (unsigned int)f32_to_bf16(acc[2 * k] * scale) |
           ((unsigned int)f32_to_bf16(acc[2 * k + 1] * scale) << 16);
  unsigned int* dst = a16 + (size_t)node * 64 + cb * 8;   // row = 64 uints
  *(uint4*)dst       = make_uint4(u[0], u[1], u[2], u[3]);
  *(uint4*)(dst + 4) = make_uint4(u[4], u[5], u[6], u[7]);
}

// ---- layer-2 GEMM: out[N,128] = [agg2|h](bf16) @ Wt(bf16) + b2, MFMA --------
__global__ __launch_bounds__(256) void k_gemm(const unsigned short* __restrict__ a16,
                                              const unsigned short* __restrict__ h16,
                                              const unsigned short* __restrict__ wt,
                                              const float* __restrict__ b2,
                                              float* __restrict__ out, int nrows) {
  __shared__ unsigned short bs[64 * 264];   // 33792 B
  int half = blockIdx.x & 1;
  int tg   = blockIdx.x >> 1;

#pragma unroll
  for (int i = 0; i < 8; ++i) {
    int c = threadIdx.x + i * 256;          // 0..2047
    int row = c >> 5, off = c & 31;         // off in 16B units
    *(uint4*)(bs + row * 264 + off * 8) =
        *(const uint4*)(wt + ((size_t)(half * 64 + row)) * 256 + off * 8);
  }
  __syncthreads();

  int wv   = threadIdx.x >> 6;
  int lane = threadIdx.x & 63;
  int m16 = lane & 15, quad = lane >> 4;
  int tile = tg * 4 + wv;
  if (tile * 16 >= nrows) return;

  int r  = tile * 16 + m16;
  int rc = r < nrows ? r : nrows - 1;
  const unsigned short* arow = a16 + (size_t)rc * 128 + quad * 8;
  const unsigned short* hrow = h16 + (size_t)rc * 128 + quad * 8;

  s16x8 afrag[8];
#pragma unroll
  for (int c4 = 0; c4 < 4; ++c4) {
    afrag[c4]     = *(const s16x8*)(arow + c4 * 32);   // A[m][k], k-chunk c4
    afrag[4 + c4] = *(const s16x8*)(hrow + c4 * 32);
  }

  f32x4 acc[4];
#pragma unroll
  for (int t = 0; t < 4; ++t) acc[t] = (f32x4){0.f, 0.f, 0.f, 0.f};

  const unsigned short* bbase = bs + m16 * 264 + quad * 8;
#pragma unroll
  for (int ch = 0; ch < 8; ++ch) {
#pragma unroll
    for (int t = 0; t < 4; ++t) {
      s16x8 bf = *(const s16x8*)(bbase + t * 16 * 264 + ch * 32); // B[k][n]
      acc[t] = __builtin_amdgcn_mfma_f32_16x16x32_bf16(afrag[ch], bf, acc[t], 0, 0, 0);
    }
  }

#pragma unroll
  for (int t = 0; t < 4; ++t) {
    int col = half * 64 + t * 16 + m16;
    float bias = b2[col];
#pragma unroll
    for (int i = 0; i < 4; ++i) {
      int row = tile * 16 + quad * 4 + i;   // C/D: col=lane&15, row=quad*4+reg
      if (row < nrows) out[(size_t)row * 128 + col] = acc[t][i] + bias;
    }
  }
}

// ---------------------------------------------------------------------------
extern "C" void kernel_launch(void* const* d_in, const int* in_sizes, int n_in,
                              void* d_out, int out_size, void* d_ws, size_t ws_size,
                              hipStream_t stream) {
  const float* x    = (const float*)d_in[0];
  const int*   ei   = (const int*)d_in[1];
  const float* Wl1  = (const float*)d_in[2];
  const float* Wr1  = (const float*)d_in[3];
  const float* b1   = (const float*)d_in[4];
  const float* Wl2  = (const float*)d_in[5];
  const float* Wr2  = (const float*)d_in[6];
  const float* b2   = (const float*)d_in[7];
  float* out = (float*)d_out;

  const int N = in_sizes[0] / 2;     // 100000
  const int E = in_sizes[1] / 2;     // 1600000
  const int nb = (N + 127) >> 7;     // 782 buckets
  const int nblk_e = (E + EDGE_TILE - 1) / EDGE_TILE;   // 391

  // workspace carve-up (256B aligned)
  char* p = (char*)d_ws;
  auto take = [&](size_t bytes) { char* r = p; p += (bytes + 255) & ~(size_t)255; return r; };
  int* bcnt            = (int*)take(1024 * 4);
  int* bbase           = (int*)take(1025 * 4);
  unsigned short* hcnt = (unsigned short*)take((size_t)nblk_e * nb * 2);
  unsigned short* rel  = (unsigned short*)take((size_t)nblk_e * nb * 2);
  int* offs            = (int*)take((size_t)(N + 1) * 4);
  int* csr             = (int*)take((size_t)E * 4);
  unsigned int* ebuf   = (unsigned int*)take((size_t)E * 4);
  float* agg1          = (float*)take((size_t)N * 2 * 4);
  unsigned short* h16  = (unsigned short*)take((size_t)N * 128 * 2);
  unsigned short* a16  = (unsigned short*)take((size_t)N * 128 * 2);
  unsigned short* h8   = (unsigned short*)take((size_t)N * 128);
  unsigned short* wt   = (unsigned short*)take((size_t)128 * 256 * 2);

  const int ntiles = (N + 15) / 16;                      // 6250

  hipMemsetAsync(bcnt, 0, 1024 * 4, stream);

  k_bhist     <<<nblk_e, 256, 0, stream>>>(ei, bcnt, hcnt, E, nb);
  k_bscan     <<<1, 1024, 0, stream>>>(bcnt, bbase, nb, E);
  k_colpre    <<<(nb + 255) / 256, 256, 0, stream>>>(hcnt, rel, nblk_e, nb);
  k_bscatter  <<<nblk_e, 256, 0, stream>>>(ei, bbase, rel, ebuf, E, nb);
  k_bucket_csr<<<nb, 256, 0, stream>>>(ebuf, bbase, x, offs, csr, agg1, N, nb);
  k_layer1    <<<((size_t)N * 64 + 255) / 256, 256, 0, stream>>>(x, agg1, offs, Wl1, Wr1, b1,
                                                                 (unsigned int*)h16, h8, N);
  k_prepw     <<<(128 * 256) / 256, 256, 0, stream>>>(Wl2, Wr2, wt);
  k_agg2      <<<(N + 31) / 32, 256, 0, stream>>>(offs, csr, (const unsigned char*)h8,
                                                  (unsigned int*)a16, N);
  k_gemm      <<<((ntiles + 3) / 4) * 2, 256, 0, stream>>>(a16, h16, wt, b2, out, N);
}

// Round 4
// 246.287 us; speedup vs baseline: 1.4173x; 1.4173x over previous
//
#include <hip/hip_runtime.h>

// ---------------------------------------------------------------------------
// GraphSAGE 2-layer, mean aggregation.
//   L1: h = relu( mean_nbr(x) @ W_l1 + x @ W_r1 + b1 )   (IN=2 -> aggregate x first)
//   L2: out = mean_nbr(h) @ W_l2 + h @ W_r2 + b2
// R2: CSR via 2-level MSD binning (bucket = dst>>7).
// R4: k_agg2 gathers h in fp8 e4m3; ebuf packed to 1 uint.
// R6: k_agg2: 8 nodes/wave, 8 lanes/node, 16 cols/lane; k_agg1 folded into
//     k_bucket_csr (x-sum via LDS float atomics).
// R7: FAILED (global counting sort): 1-block scan 233us; device-scope random
//     atomics ~200us. Reverted.
// R8: NEUTRAL (XCD-seg ebuf): run length per (block,bucket) unchanged. Reverted.
// R9: k_bscatter pass-1 eliminated via per-(block,bucket) bases (hcnt/rel).
//     FAILED on impl: k_colpre serial column scan = 96us latency-bound
//     (0.14% occ, 391 dependent loads/thread) — same class as R7's k_scan.
//     k_agg2 unroll-4 also suspected +25us (VGPR pressure). 
// R10: k_colscan: parallel column prefix — one workgroup per bucket, thread
//     owns 2 of 391 entries, pair-sum + 8-step LDS scan, write rel. ~5us.
//     k_agg2 reverted to unroll-2 (R0-proven).
// ---------------------------------------------------------------------------

using f32x4 = __attribute__((ext_vector_type(4))) float;
using f32x2 = __attribute__((ext_vector_type(2))) float;
using s16x8 = __attribute__((ext_vector_type(8))) short;

__device__ __forceinline__ unsigned short f32_to_bf16(float f) {
  unsigned int u = __float_as_uint(f);
  u += 0x7fffu + ((u >> 16) & 1u);          // round-to-nearest-even
  return (unsigned short)(u >> 16);
}

#define EDGE_TILE 4096

// ---- bin pass 1: bucket histogram; stores per-block row + bucket totals -----
__global__ __launch_bounds__(256) void k_bhist(const int* __restrict__ ei, int* __restrict__ bcnt,
                                               unsigned short* __restrict__ hcnt, int E, int nb) {
  __shared__ int h[1024];
  int t = threadIdx.x;
  for (int i = t; i < nb; i += 256) h[i] = 0;
  __syncthreads();
  int tbeg = blockIdx.x * EDGE_TILE;
  int tend = min(tbeg + EDGE_TILE, E);
  const int* dstp = ei + E;
  for (int i = tbeg + t; i < tend; i += 256) atomicAdd(&h[dstp[i] >> 7], 1);
  __syncthreads();
  unsigned short* hr = hcnt + (size_t)blockIdx.x * nb;
  for (int i = t; i < nb; i += 256) {
    int c = h[i];
    hr[i] = (unsigned short)c;              // c <= EDGE_TILE=4096, fits u16
    if (c) atomicAdd(&bcnt[i], c);
  }
}

// ---- bin pass 2a: scan bucket totals -> bucket bases ------------------------
__global__ __launch_bounds__(1024) void k_bscan(const int* __restrict__ bcnt, int* __restrict__ bbase,
                                                int nb, int E) {
  __shared__ int sm[2][1024];
  int t = threadIdx.x;
  int v0 = (t < nb) ? bcnt[t] : 0;
  sm[0][t] = v0;
  __syncthreads();
  int src = 0;
  for (int st = 1; st < 1024; st <<= 1) {
    int v = sm[src][t];
    if (t >= st) v += sm[src][t - st];
    sm[src ^ 1][t] = v; __syncthreads(); src ^= 1;
  }
  if (t < nb) bbase[t] = sm[src][t] - v0;   // exclusive prefix
  if (t == 0) bbase[nb] = E;
}

// ---- bin pass 2b: per-(block,bucket) prefix along block axis (PARALLEL) -----
// One workgroup per bucket. Thread t owns column entries 2t, 2t+1 (nblk=391
// <= 512). Pair-sum -> 256-wide Hillis-Steele scan in LDS -> write rel.
__global__ __launch_bounds__(256) void k_colscan(const unsigned short* __restrict__ hcnt,
                                                 unsigned short* __restrict__ rel,
                                                 int nblk, int nb) {
  __shared__ int sm[2][256];
  int b = blockIdx.x;
  int t = threadIdx.x;
  int e0 = 2 * t, e1 = 2 * t + 1;
  int a = (e0 < nblk) ? (int)hcnt[(size_t)e0 * nb + b] : 0;
  int c = (e1 < nblk) ? (int)hcnt[(size_t)e1 * nb + b] : 0;
  int s = a + c;
  sm[0][t] = s;
  __syncthreads();
  int src = 0;
  for (int st = 1; st < 256; st <<= 1) {
    int v = sm[src][t];
    if (t >= st) v += sm[src][t - st];
    sm[src ^ 1][t] = v; __syncthreads(); src ^= 1;
  }
  int excl = sm[src][t] - s;                // exclusive prefix of pair-sums
  if (e0 < nblk) rel[(size_t)e0 * nb + b] = (unsigned short)excl;
  if (e1 < nblk) rel[(size_t)e1 * nb + b] = (unsigned short)(excl + a);
}

// ---- bin pass 3: scatter packed (src<<7 | dst&127) at precomputed bases -----
__global__ __launch_bounds__(256) void k_bscatter(const int* __restrict__ ei,
                                                  const int* __restrict__ bbase,
                                                  const unsigned short* __restrict__ rel,
                                                  unsigned int* __restrict__ ebuf, int E, int nb) {
  __shared__ int h[1024];                    // in-block rank cursors
  __shared__ int base[1024];
  int t = threadIdx.x;
  const unsigned short* rr = rel + (size_t)blockIdx.x * nb;
  for (int i = t; i < nb; i += 256) {
    h[i] = 0;
    base[i] = bbase[i] + (int)rr[i];
  }
  __syncthreads();
  int tbeg = blockIdx.x * EDGE_TILE;
  int tend = min(tbeg + EDGE_TILE, E);
  const int* srcp = ei;
  const int* dstp = ei + E;
  for (int i = tbeg + t; i < tend; i += 256) {
    int d = dstp[i];
    int b = d >> 7;
    int r = atomicAdd(&h[b], 1);
    ebuf[base[b] + r] = ((unsigned)srcp[i] << 7) | (unsigned)(d & 127);
  }
}

// ---- bin pass 4: per-bucket CSR build + layer-1 x aggregation ---------------
__global__ __launch_bounds__(256) void k_bucket_csr(const unsigned int* __restrict__ ebuf,
                                                    const int* __restrict__ bbase,
                                                    const float* __restrict__ x,
                                                    int* __restrict__ offs, int* __restrict__ csr,
                                                    float* __restrict__ agg1,
                                                    int N, int nb) {
  __shared__ int deg[128];
  __shared__ int loff[128];
  __shared__ int cur[128];
  __shared__ float sx0[128];
  __shared__ float sx1[128];
  int b = blockIdx.x;
  int t = threadIdx.x;
  int lo = bbase[b], hi = bbase[b + 1];
  if (t < 128) { deg[t] = 0; sx0[t] = 0.f; sx1[t] = 0.f; }
  __syncthreads();
  const float2* x2 = (const float2*)x;
  for (int i = lo + t; i < hi; i += 256) {
    unsigned int e = ebuf[i];
    int d = e & 127;
    float2 v = x2[e >> 7];
    atomicAdd(&deg[d], 1);
    atomicAdd(&sx0[d], v.x);
    atomicAdd(&sx1[d], v.y);
  }
  __syncthreads();
  if (t < 128) loff[t] = deg[t];
  __syncthreads();
  for (int st = 1; st < 128; st <<= 1) {
    int v = 0;
    if (t < 128 && t >= st) v = loff[t - st];
    __syncthreads();
    if (t < 128) loff[t] += v;
    __syncthreads();
  }
  if (t < 128) {
    int ex = loff[t] - deg[t];                 // exclusive prefix
    cur[t] = ex;
    int node = b * 128 + t;
    if (node < N) {
      offs[node] = lo + ex;
      agg1[2 * node]     = sx0[t];
      agg1[2 * node + 1] = sx1[t];
    }
  }
  if (b == nb - 1 && t == 0) offs[N] = hi;
  __syncthreads();
  for (int i = lo + t; i < hi; i += 256) {
    unsigned int e = ebuf[i];
    int r = atomicAdd(&cur[e & 127], 1);
    csr[lo + r] = (int)(e >> 7);
  }
}

// ---- layer-1 dense: h = relu(...), bf16 + fp8 out; 2 cols/thread ------------
__global__ __launch_bounds__(256) void k_layer1(const float* __restrict__ x, const float* __restrict__ agg1,
                                                const int* __restrict__ offs,
                                                const float* __restrict__ Wl, const float* __restrict__ Wr,
                                                const float* __restrict__ b1,
                                                unsigned int* __restrict__ h16,
                                                unsigned short* __restrict__ h8, int n) {
  int gid = blockIdx.x * 256 + threadIdx.x;
  int node = gid >> 6;
  if (node >= n) return;
  int c = (gid & 63) * 2;
  int deg = offs[node + 1] - offs[node];
  float sc = 1.0f / (float)max(deg, 1);
  float a0 = agg1[2 * node] * sc, a1 = agg1[2 * node + 1] * sc;
  float x0 = x[2 * node], x1 = x[2 * node + 1];
  float r0 = fmaf(a0, Wl[c],     fmaf(a1, Wl[128 + c],     fmaf(x0, Wr[c],     fmaf(x1, Wr[128 + c],     b1[c]))));
  float r1 = fmaf(a0, Wl[c + 1], fmaf(a1, Wl[128 + c + 1], fmaf(x0, Wr[c + 1], fmaf(x1, Wr[128 + c + 1], b1[c + 1]))));
  r0 = r0 > 0.f ? r0 : 0.f;
  r1 = r1 > 0.f ? r1 : 0.f;
  unsigned int packed = (unsigned int)f32_to_bf16(r0) | ((unsigned int)f32_to_bf16(r1) << 16);
  h16[(size_t)node * 64 + (gid & 63)] = packed;
  unsigned int p8 = (unsigned int)__builtin_amdgcn_cvt_pk_fp8_f32(r0, r1, 0, false);
  h8[(size_t)node * 64 + (gid & 63)] = (unsigned short)(p8 & 0xffffu);
}

// ---- prep: Wt[col][k] bf16, k<128 from W_l2, k>=128 from W_r2 ---------------
__global__ __launch_bounds__(256) void k_prepw(const float* __restrict__ Wl2, const float* __restrict__ Wr2,
                                               unsigned short* __restrict__ wt) {
  int tid = blockIdx.x * 256 + threadIdx.x;   // tid = c*256 + k
  if (tid >= 128 * 256) return;
  int c = tid >> 8, k = tid & 255;
  float v = (k < 128) ? Wl2[k * 128 + c] : Wr2[(k - 128) * 128 + c];
  wt[tid] = f32_to_bf16(v);
}

// ---- layer-2 aggregation: 8 nodes/wave, 8 lanes/node, 16 cols/lane ----------
#define ACC8(v)                                                                              \
  do {                                                                                       \
    f32x2 p;                                                                                 \
    p = __builtin_amdgcn_cvt_pk_f32_fp8((int)(v).x, false); acc[0] += p[0];  acc[1] += p[1]; \
    p = __builtin_amdgcn_cvt_pk_f32_fp8((int)(v).x, true);  acc[2] += p[0];  acc[3] += p[1]; \
    p = __builtin_amdgcn_cvt_pk_f32_fp8((int)(v).y, false); acc[4] += p[0];  acc[5] += p[1]; \
    p = __builtin_amdgcn_cvt_pk_f32_fp8((int)(v).y, true);  acc[6] += p[0];  acc[7] += p[1]; \
    p = __builtin_amdgcn_cvt_pk_f32_fp8((int)(v).z, false); acc[8] += p[0];  acc[9] += p[1]; \
    p = __builtin_amdgcn_cvt_pk_f32_fp8((int)(v).z, true);  acc[10] += p[0]; acc[11] += p[1];\
    p = __builtin_amdgcn_cvt_pk_f32_fp8((int)(v).w, false); acc[12] += p[0]; acc[13] += p[1];\
    p = __builtin_amdgcn_cvt_pk_f32_fp8((int)(v).w, true);  acc[14] += p[0]; acc[15] += p[1];\
  } while (0)

__global__ __launch_bounds__(256) void k_agg2(const int* __restrict__ offs, const int* __restrict__ csr,
                                              const unsigned char* __restrict__ h8,
                                              unsigned int* __restrict__ a16, int n) {
  int wv   = threadIdx.x >> 6;
  int lane = threadIdx.x & 63;
  int sub  = lane >> 3;          // node slot within wave: 0..7
  int cb   = lane & 7;           // 16-col block: cols cb*16 .. cb*16+15
  int node = blockIdx.x * 32 + wv * 8 + sub;
  if (node >= n) return;
  int beg = offs[node];
  int end = offs[node + 1];
  int deg = end - beg;
  const unsigned char* hb = h8 + cb * 16;

  float acc[16];
#pragma unroll
  for (int j = 0; j < 16; ++j) acc[j] = 0.f;

  int t = 0;
  for (; t + 1 < deg; t += 2) {
    int s0 = csr[beg + t];
    int s1 = csr[beg + t + 1];
    uint4 v0 = *(const uint4*)(hb + (size_t)s0 * 128);
    uint4 v1 = *(const uint4*)(hb + (size_t)s1 * 128);
    ACC8(v0);
    ACC8(v1);
  }
  if (t < deg) {
    int s0 = csr[beg + t];
    uint4 v0 = *(const uint4*)(hb + (size_t)s0 * 128);
    ACC8(v0);
  }

  float scale = 1.0f / (float)max(deg, 1);
  unsigned int u[8];
#pragma unroll
  for (int k = 0; k < 8; ++k)
    u[k] = (unsigned int)f32_to_bf16(acc[2 * k] * scale) |
           ((unsigned int)f32_to_bf16(acc[2 * k + 1] * scale) << 16);
  unsigned int* dst = a16 + (size_t)node * 64 + cb * 8;   // row = 64 uints
  *(uint4*)dst       = make_uint4(u[0], u[1], u[2], u[3]);
  *(uint4*)(dst + 4) = make_uint4(u[4], u[5], u[6], u[7]);
}

// ---- layer-2 GEMM: out[N,128] = [agg2|h](bf16) @ Wt(bf16) + b2, MFMA --------
__global__ __launch_bounds__(256) void k_gemm(const unsigned short* __restrict__ a16,
                                              const unsigned short* __restrict__ h16,
                                              const unsigned short* __restrict__ wt,
                                              const float* __restrict__ b2,
                                              float* __restrict__ out, int nrows) {
  __shared__ unsigned short bs[64 * 264];   // 33792 B
  int half = blockIdx.x & 1;
  int tg   = blockIdx.x >> 1;

#pragma unroll
  for (int i = 0; i < 8; ++i) {
    int c = threadIdx.x + i * 256;          // 0..2047
    int row = c >> 5, off = c & 31;         // off in 16B units
    *(uint4*)(bs + row * 264 + off * 8) =
        *(const uint4*)(wt + ((size_t)(half * 64 + row)) * 256 + off * 8);
  }
  __syncthreads();

  int wv   = threadIdx.x >> 6;
  int lane = threadIdx.x & 63;
  int m16 = lane & 15, quad = lane >> 4;
  int tile = tg * 4 + wv;
  if (tile * 16 >= nrows) return;

  int r  = tile * 16 + m16;
  int rc = r < nrows ? r : nrows - 1;
  const unsigned short* arow = a16 + (size_t)rc * 128 + quad * 8;
  const unsigned short* hrow = h16 + (size_t)rc * 128 + quad * 8;

  s16x8 afrag[8];
#pragma unroll
  for (int c4 = 0; c4 < 4; ++c4) {
    afrag[c4]     = *(const s16x8*)(arow + c4 * 32);   // A[m][k], k-chunk c4
    afrag[4 + c4] = *(const s16x8*)(hrow + c4 * 32);
  }

  f32x4 acc[4];
#pragma unroll
  for (int t = 0; t < 4; ++t) acc[t] = (f32x4){0.f, 0.f, 0.f, 0.f};

  const unsigned short* bbase = bs + m16 * 264 + quad * 8;
#pragma unroll
  for (int ch = 0; ch < 8; ++ch) {
#pragma unroll
    for (int t = 0; t < 4; ++t) {
      s16x8 bf = *(const s16x8*)(bbase + t * 16 * 264 + ch * 32); // B[k][n]
      acc[t] = __builtin_amdgcn_mfma_f32_16x16x32_bf16(afrag[ch], bf, acc[t], 0, 0, 0);
    }
  }

#pragma unroll
  for (int t = 0; t < 4; ++t) {
    int col = half * 64 + t * 16 + m16;
    float bias = b2[col];
#pragma unroll
    for (int i = 0; i < 4; ++i) {
      int row = tile * 16 + quad * 4 + i;   // C/D: col=lane&15, row=quad*4+reg
      if (row < nrows) out[(size_t)row * 128 + col] = acc[t][i] + bias;
    }
  }
}

// ---------------------------------------------------------------------------
extern "C" void kernel_launch(void* const* d_in, const int* in_sizes, int n_in,
                              void* d_out, int out_size, void* d_ws, size_t ws_size,
                              hipStream_t stream) {
  const float* x    = (const float*)d_in[0];
  const int*   ei   = (const int*)d_in[1];
  const float* Wl1  = (const float*)d_in[2];
  const float* Wr1  = (const float*)d_in[3];
  const float* b1   = (const float*)d_in[4];
  const float* Wl2  = (const float*)d_in[5];
  const float* Wr2  = (const float*)d_in[6];
  const float* b2   = (const float*)d_in[7];
  float* out = (float*)d_out;

  const int N = in_sizes[0] / 2;     // 100000
  const int E = in_sizes[1] / 2;     // 1600000
  const int nb = (N + 127) >> 7;     // 782 buckets
  const int nblk_e = (E + EDGE_TILE - 1) / EDGE_TILE;   // 391

  // workspace carve-up (256B aligned)
  char* p = (char*)d_ws;
  auto take = [&](size_t bytes) { char* r = p; p += (bytes + 255) & ~(size_t)255; return r; };
  int* bcnt            = (int*)take(1024 * 4);
  int* bbase           = (int*)take(1025 * 4);
  unsigned short* hcnt = (unsigned short*)take((size_t)nblk_e * nb * 2);
  unsigned short* rel  = (unsigned short*)take((size_t)nblk_e * nb * 2);
  int* offs            = (int*)take((size_t)(N + 1) * 4);
  int* csr             = (int*)take((size_t)E * 4);
  unsigned int* ebuf   = (unsigned int*)take((size_t)E * 4);
  float* agg1          = (float*)take((size_t)N * 2 * 4);
  unsigned short* h16  = (unsigned short*)take((size_t)N * 128 * 2);
  unsigned short* a16  = (unsigned short*)take((size_t)N * 128 * 2);
  unsigned short* h8   = (unsigned short*)take((size_t)N * 128);
  unsigned short* wt   = (unsigned short*)take((size_t)128 * 256 * 2);

  const int ntiles = (N + 15) / 16;                      // 6250

  hipMemsetAsync(bcnt, 0, 1024 * 4, stream);

  k_bhist     <<<nblk_e, 256, 0, stream>>>(ei, bcnt, hcnt, E, nb);
  k_bscan     <<<1, 1024, 0, stream>>>(bcnt, bbase, nb, E);
  k_colscan   <<<nb, 256, 0, stream>>>(hcnt, rel, nblk_e, nb);
  k_bscatter  <<<nblk_e, 256, 0, stream>>>(ei, bbase, rel, ebuf, E, nb);
  k_bucket_csr<<<nb, 256, 0, stream>>>(ebuf, bbase, x, offs, csr, agg1, N, nb);
  k_layer1    <<<((size_t)N * 64 + 255) / 256, 256, 0, stream>>>(x, agg1, offs, Wl1, Wr1, b1,
                                                                 (unsigned int*)h16, h8, N);
  k_prepw     <<<(128 * 256) / 256, 256, 0, stream>>>(Wl2, Wr2, wt);
  k_agg2      <<<(N + 31) / 32, 256, 0, stream>>>(offs, csr, (const unsigned char*)h8,
                                                  (unsigned int*)a16, N);
  k_gemm      <<<((ntiles + 3) / 4) * 2, 256, 0, stream>>>(a16, h16, wt, b2, out, N);
}